// Round 3
// baseline (690.004 us; speedup 1.0000x reference)
//
#include <hip/hip_runtime.h>
#include <math.h>

#define B_ 256
#define L_ 256
#define V_ 2048
#define DIN_ 128
#define H_ 256
#define NODES_ 511

typedef _Float16 half8 __attribute__((ext_vector_type(8)));
typedef float f32x4 __attribute__((ext_vector_type(4)));

__device__ __forceinline__ float sigm(float x) { return 1.f / (1.f + __expf(-x)); }
__device__ __forceinline__ float tanh_f(float x) {
    float xc = fminf(fmaxf(x, -15.f), 15.f);
    float e = __expf(2.f * xc);
    return (e - 1.f) / (e + 1.f);
}

// WallT[n][k] fp16, n = g*256 + t (g: 0=i,1=o,2=u,3=f0,4=f1), k: [0,128)=x, [128,384)=h1, [384,640)=h2
__global__ void build_wallT(_Float16* __restrict__ WT,
    const float* __restrict__ Wioux, const float* __restrict__ Wfx,
    const float* __restrict__ Wiouh1, const float* __restrict__ Wfh11, const float* __restrict__ Wfh21,
    const float* __restrict__ Wiouh2, const float* __restrict__ Wfh12, const float* __restrict__ Wfh22)
{
    int e = blockIdx.x * 256 + threadIdx.x;   // < 1280*640 = 819200
    int nn = e / 640, k = e - nn * 640;
    int g = nn >> 8, t = nn & 255;
    float v;
    if (k < 128) {
        v = (g < 3) ? Wioux[k * 768 + nn] : Wfx[k * 256 + t];
    } else if (k < 384) {
        int kp = k - 128;
        v = (g < 3) ? Wiouh1[kp * 768 + nn] : ((g == 3) ? Wfh11[kp * 256 + t] : Wfh21[kp * 256 + t]);
    } else {
        int kp = k - 384;
        v = (g < 3) ? Wiouh2[kp * 768 + nn] : ((g == 3) ? Wfh12[kp * 256 + t] : Wfh22[kp * 256 + t]);
    }
    WT[e] = (_Float16)v;
}

__global__ void build_bias(float* __restrict__ bias,
    const float* __restrict__ bioux, const float* __restrict__ biouh1, const float* __restrict__ biouh2,
    const float* __restrict__ bfx, const float* __restrict__ bfh11, const float* __restrict__ bfh12,
    const float* __restrict__ bfh21, const float* __restrict__ bfh22)
{
    int e = blockIdx.x * 256 + threadIdx.x;
    if (e >= 1280) return;
    int g = e >> 8, t = e & 255;
    float v;
    if (g < 3)       v = bioux[e] + biouh1[e] + biouh2[e];
    else if (g == 3) v = bfx[t] + bfh11[t] + bfh12[t];
    else             v = bfx[t] + bfh21[t] + bfh22[t];
    bias[e] = v;
}

// emb -> fp16, with row 0 zeroed (reference does emb.at[0].set(0))
__global__ void build_embh(_Float16* __restrict__ EH, const float* __restrict__ emb) {
    int e = blockIdx.x * 256 + threadIdx.x;   // < 2048*128
    EH[e] = (e < DIN_) ? (_Float16)0.f : (_Float16)emb[e];
}

// Register-only MFMA tree-level cell. No LDS, no barriers.
// Block 256 thr = 4 waves; waves split FEATURES: wave w -> feats blockIdx.y*64 + w*16.
// Each wave: 64 rows (R=4 frags of 16) x 16 feats x G gates (C=G frags). 20 MFMA : 9 loads.
// A row r: [embh[ids[r]] (128) | h_prev[2r],h_prev[2r+1] (512)] fp16, gathered per-lane in
// exact MFMA fragment layout (lane=(row l&15, kseg lane>>4), 16B/lane, 64B-aligned spans).
template<int G, int KTOT>
__global__ __launch_bounds__(256) void cell_reg(
    const _Float16* __restrict__ WT, const float* __restrict__ bias,
    const int* __restrict__ ids, const _Float16* __restrict__ embh,
    const _Float16* __restrict__ h_prev, const float* __restrict__ c_prev,
    _Float16* __restrict__ h_out, float* __restrict__ c_out,
    int n, int ln, int off)
{
    constexpr int NSTEP = KTOT / 32;
    const int tid = threadIdx.x;
    const int lane = tid & 63;
    const int w = tid >> 6;
    const int l15 = lane & 15, lg = lane >> 4;
    const int rowB = blockIdx.x * 64;
    const int fcol = blockIdx.y * 64 + w * 16 + l15;   // this lane's output feature

    // per-lane A-row base pointers (fragment rows rt*16 + l15)
    const _Float16* aX[4];
    const _Float16* aH[4];
    #pragma unroll
    for (int rt = 0; rt < 4; ++rt) {
        int r = rowB + rt * 16 + l15;
        int b = r >> ln, j = r & (n - 1);
        int id = ids[b * NODES_ + off + j];
        aX[rt] = embh + (size_t)id * DIN_ + lg * 8;
        aH[rt] = h_prev + (size_t)r * (2 * H_) + lg * 8 - DIN_;  // +k0 valid for k0>=128
    }
    const _Float16* bP[G];
    #pragma unroll
    for (int g = 0; g < G; ++g)
        bP[g] = WT + (size_t)(g * 256 + fcol) * 640 + lg * 8;

    // biases (uniform across rows; load early)
    float bi = bias[fcol], bo = bias[H_ + fcol], bu = bias[2 * H_ + fcol];
    float bf0 = (G == 5) ? bias[3 * H_ + fcol] : 0.f;
    float bf1 = (G == 5) ? bias[4 * H_ + fcol] : 0.f;

    f32x4 acc[4][G];
    #pragma unroll
    for (int rt = 0; rt < 4; ++rt)
        #pragma unroll
        for (int g = 0; g < G; ++g) acc[rt][g] = (f32x4)0.f;

    half8 aF[2][4], bF[2][G];
    // prologue: step 0 (k0 = 0 < 128 -> embedding part)
    #pragma unroll
    for (int rt = 0; rt < 4; ++rt) aF[0][rt] = *(const half8*)(aX[rt]);
    #pragma unroll
    for (int g = 0; g < G; ++g)    bF[0][g]  = *(const half8*)(bP[g]);

    #pragma unroll
    for (int s = 0; s < NSTEP; ++s) {
        const int cur = s & 1, nxt = cur ^ 1;
        const int k1 = (s + 1) * 32;
        if (s + 1 < NSTEP) {
            #pragma unroll
            for (int rt = 0; rt < 4; ++rt)
                aF[nxt][rt] = (k1 < DIN_) ? *(const half8*)(aX[rt] + k1)
                                          : *(const half8*)(aH[rt] + k1);
            #pragma unroll
            for (int g = 0; g < G; ++g)
                bF[nxt][g] = *(const half8*)(bP[g] + k1);
        }
        #pragma unroll
        for (int rt = 0; rt < 4; ++rt)
            #pragma unroll
            for (int g = 0; g < G; ++g)
                acc[rt][g] = __builtin_amdgcn_mfma_f32_16x16x32_f16(aF[cur][rt], bF[cur][g], acc[rt][g], 0, 0, 0);
    }

    // fused epilogue: D row = (lane>>4)*4 + q, col = lane&15 (verified layout)
    #pragma unroll
    for (int rt = 0; rt < 4; ++rt) {
        int row0 = rowB + rt * 16 + lg * 4;
        #pragma unroll
        for (int q = 0; q < 4; ++q) {
            int row = row0 + q;
            float vi = sigm(acc[rt][0][q] + bi);
            float vo = sigm(acc[rt][1][q] + bo);
            float vu = tanh_f(acc[rt][2][q] + bu);
            float c;
            if constexpr (G == 5) {
                float vf0 = sigm(acc[rt][3][q] + bf0);
                float vf1 = sigm(acc[rt][4][q] + bf1);
                const float* cpp = c_prev + (size_t)row * (2 * H_) + fcol;
                c = vi * vu + vf0 * cpp[0] + vf1 * cpp[H_];
            } else {
                c = vi * vu;
            }
            size_t ob = (size_t)row * H_ + fcol;
            h_out[ob] = (_Float16)(vo * tanh_f(c));
            c_out[ob] = c;
        }
    }
}

// pred[b] = relu(h_root[b] @ Wl1 + bl1) @ Wl2 + bl2
__global__ void head_kernel(const _Float16* __restrict__ hroot,
    const float* __restrict__ Wl1, const float* __restrict__ bl1,
    const float* __restrict__ Wl2, const float* __restrict__ bl2,
    float* __restrict__ out)
{
    __shared__ float hrow[H_];
    __shared__ float red[256];
    int b = blockIdx.x; int tid = threadIdx.x;
    hrow[tid] = (float)hroot[(size_t)b * H_ + tid];
    __syncthreads();
    float v = 0.f;
    if (tid < 100) {
        float s = bl1[tid];
        for (int k = 0; k < H_; ++k) s = fmaf(hrow[k], Wl1[k * 100 + tid], s);
        v = fmaxf(s, 0.f) * Wl2[tid];
    }
    red[tid] = v;
    __syncthreads();
    for (int s = 128; s > 0; s >>= 1) { if (tid < s) red[tid] += red[tid + s]; __syncthreads(); }
    if (tid == 0) out[b] = red[0] + bl2[0];
}

extern "C" void kernel_launch(void* const* d_in, const int* in_sizes, int n_in,
                              void* d_out, int out_size, void* d_ws, size_t ws_size,
                              hipStream_t stream) {
    const int*   ids    = (const int*)d_in[0];
    const float* emb    = (const float*)d_in[1];
    const float* Wioux  = (const float*)d_in[2];
    const float* bioux  = (const float*)d_in[3];
    const float* Wiouh1 = (const float*)d_in[4];
    const float* biouh1 = (const float*)d_in[5];
    const float* Wiouh2 = (const float*)d_in[6];
    const float* biouh2 = (const float*)d_in[7];
    const float* Wfx    = (const float*)d_in[8];
    const float* bfx    = (const float*)d_in[9];
    const float* Wfh11  = (const float*)d_in[10];
    const float* bfh11  = (const float*)d_in[11];
    const float* Wfh12  = (const float*)d_in[12];
    const float* bfh12  = (const float*)d_in[13];
    const float* Wfh21  = (const float*)d_in[14];
    const float* bfh21  = (const float*)d_in[15];
    const float* Wfh22  = (const float*)d_in[16];
    const float* bfh22  = (const float*)d_in[17];
    const float* Wl1    = (const float*)d_in[18];
    const float* bl1    = (const float*)d_in[19];
    const float* Wl2    = (const float*)d_in[20];
    const float* bl2    = (const float*)d_in[21];
    float* out = (float*)d_out;

    // ws layout (bytes):
    // WT 1,638,400 | EH 524,288 | bias 5,120 | hA 33,554,432 | hB 16,777,216 | cA 67,108,864 | cB 33,554,432
    char* wsb = (char*)d_ws;
    _Float16* WT   = (_Float16*)(wsb);
    _Float16* EH   = (_Float16*)(wsb + 1638400);
    float*    bias = (float*)(wsb + 2162688);
    _Float16* hA   = (_Float16*)(wsb + 2167808);
    _Float16* hB   = (_Float16*)(wsb + 35722240);
    float*    cA   = (float*)(wsb + 52499456);
    float*    cB   = (float*)(wsb + 119608320);

    build_wallT<<<dim3(3200), 256, 0, stream>>>(WT, Wioux, Wfx, Wiouh1, Wfh11, Wfh21, Wiouh2, Wfh12, Wfh22);
    build_bias<<<dim3(5), 256, 0, stream>>>(bias, bioux, biouh1, biouh2, bfx, bfh11, bfh12, bfh21, bfh22);
    build_embh<<<dim3(1024), 256, 0, stream>>>(EH, emb);

    // level 0: K=128 (x only), gates iou
    cell_reg<3, 128><<<dim3(1024, 4), 256, 0, stream>>>(WT, bias, ids, EH, hA, cA, hA, cA, 256, 8, 0);

    _Float16 *hp = hA, *hn = hB;
    float    *cp = cA, *cn = cB;
    int off = 256, n = 128, ln = 7;
    for (int lvl = 1; lvl < 9; ++lvl) {
        int M = B_ * n;
        cell_reg<5, 640><<<dim3(M / 64, 4), 256, 0, stream>>>(WT, bias, ids, EH, hp, cp, hn, cn, n, ln, off);
        off += n; n >>= 1; ln -= 1;
        _Float16* t1 = hp; hp = hn; hn = t1;
        float*    t2 = cp; cp = cn; cn = t2;
    }

    head_kernel<<<dim3(256), 256, 0, stream>>>(hp, Wl1, bl1, Wl2, bl2, out);
}

// Round 4
// 375.355 us; speedup vs baseline: 1.8383x; 1.8383x over previous
//
#include <hip/hip_runtime.h>
#include <math.h>

#define B_ 256
#define L_ 256
#define V_ 2048
#define DIN_ 128
#define H_ 256
#define NODES_ 511

typedef _Float16 half8 __attribute__((ext_vector_type(8)));
typedef float f32x4 __attribute__((ext_vector_type(4)));

__device__ __forceinline__ float sigm(float x) { return 1.f / (1.f + __expf(-x)); }
__device__ __forceinline__ float tanh_f(float x) {
    float xc = fminf(fmaxf(x, -15.f), 15.f);
    float e = __expf(2.f * xc);
    return (e - 1.f) / (e + 1.f);
}
__device__ __forceinline__ void gload16(const void* g, void* l) {
    __builtin_amdgcn_global_load_lds((const __attribute__((address_space(1))) unsigned int*)g,
                                     (__attribute__((address_space(3))) unsigned int*)l, 16, 0, 0);
}

// WTh[n][k] fp16: h-part weights only. n = g*256+t (g:0=i,1=o,2=u,3=f0,4=f1), k:[0,256)=h1,[256,512)=h2
__global__ void build_WTh(_Float16* __restrict__ WTh,
    const float* __restrict__ Wiouh1, const float* __restrict__ Wfh11, const float* __restrict__ Wfh21,
    const float* __restrict__ Wiouh2, const float* __restrict__ Wfh12, const float* __restrict__ Wfh22)
{
    int e = blockIdx.x * 256 + threadIdx.x;   // < 1280*512
    int nn = e >> 9, k = e & 511;
    int g = nn >> 8, t = nn & 255;
    float v;
    if (k < 256) {
        v = (g < 3) ? Wiouh1[k * 768 + nn] : ((g == 3) ? Wfh11[k * 256 + t] : Wfh21[k * 256 + t]);
    } else {
        int kp = k - 256;
        v = (g < 3) ? Wiouh2[kp * 768 + nn] : ((g == 3) ? Wfh12[kp * 256 + t] : Wfh22[kp * 256 + t]);
    }
    WTh[e] = (_Float16)v;
}

// tab[id][col] f32 = emb(id,:) @ Wx_fused(:,col) + bias_total(col); emb row 0 zeroed.
// col = g*256+t. fp32 blocked GEMM: 64x64 tile, K=128 in chunks of 32.
__global__ __launch_bounds__(256) void build_table(float* __restrict__ tab, const float* __restrict__ emb,
    const float* __restrict__ Wioux, const float* __restrict__ Wfx,
    const float* __restrict__ bioux, const float* __restrict__ biouh1, const float* __restrict__ biouh2,
    const float* __restrict__ bfx, const float* __restrict__ bfh11, const float* __restrict__ bfh12,
    const float* __restrict__ bfh21, const float* __restrict__ bfh22)
{
    __shared__ float As[64][33];
    __shared__ float Ws[32][65];
    const int tid = threadIdx.x, tx = tid & 15, ty = tid >> 4;
    const int i0 = blockIdx.x * 64, c0 = blockIdx.y * 64;
    const int g = c0 >> 8;                      // uniform per block (64 | 256)
    float acc[4][4];
    #pragma unroll
    for (int i = 0; i < 4; ++i)
        #pragma unroll
        for (int j = 0; j < 4; ++j) acc[i][j] = 0.f;

    for (int k0 = 0; k0 < 128; k0 += 32) {
        #pragma unroll
        for (int it = 0; it < 2; ++it) {
            int f = tid + it * 256;             // 0..511
            int row = f >> 3, kk = (f & 7) * 4;
            int gr = i0 + row;
            float4 av = (gr == 0) ? make_float4(0.f, 0.f, 0.f, 0.f)
                                  : *(const float4*)(emb + (size_t)gr * 128 + k0 + kk);
            As[row][kk] = av.x; As[row][kk + 1] = av.y; As[row][kk + 2] = av.z; As[row][kk + 3] = av.w;
            int k = f >> 4, cc = (f & 15) * 4;
            int col = c0 + cc;
            float4 wv = (g < 3) ? *(const float4*)(Wioux + (size_t)(k0 + k) * 768 + col)
                                : *(const float4*)(Wfx + (size_t)(k0 + k) * 256 + (col & 255));
            Ws[k][cc] = wv.x; Ws[k][cc + 1] = wv.y; Ws[k][cc + 2] = wv.z; Ws[k][cc + 3] = wv.w;
        }
        __syncthreads();
        #pragma unroll 8
        for (int k = 0; k < 32; ++k) {
            float a[4], w[4];
            #pragma unroll
            for (int i = 0; i < 4; ++i) a[i] = As[ty * 4 + i][k];
            #pragma unroll
            for (int j = 0; j < 4; ++j) w[j] = Ws[k][tx * 4 + j];
            #pragma unroll
            for (int i = 0; i < 4; ++i)
                #pragma unroll
                for (int j = 0; j < 4; ++j) acc[i][j] = fmaf(a[i], w[j], acc[i][j]);
        }
        __syncthreads();
    }
    #pragma unroll
    for (int j = 0; j < 4; ++j) {
        int col = c0 + tx * 4 + j; int t = col & 255;
        float bs = (g < 3) ? (bioux[col] + biouh1[col] + biouh2[col])
                 : (g == 3) ? (bfx[t] + bfh11[t] + bfh12[t])
                            : (bfx[t] + bfh21[t] + bfh22[t]);
        #pragma unroll
        for (int i = 0; i < 4; ++i)
            tab[(size_t)(i0 + ty * 4 + i) * 1280 + col] = acc[i][j] + bs;
    }
}

// Level-0 result depends only on token id: H0h/H0c[id][t]
__global__ void build_h0c0(const float* __restrict__ tab, _Float16* __restrict__ H0h, float* __restrict__ H0c) {
    int id = blockIdx.x, t = threadIdx.x;
    const float* tp = tab + (size_t)id * 1280 + t;
    float vi = sigm(tp[0]), vo = sigm(tp[256]), vu = tanh_f(tp[512]);
    float c = vi * vu;
    H0h[id * 256 + t] = (_Float16)(vo * tanh_f(c));
    H0c[id * 256 + t] = c;
}

// Tree-level cell: BM=256 rows (4 waves x 64) x BN=80 (t16 x 5 gates). K=512.
// B: LDS double-buffered via global_load_lds, 16B-seg XOR swizzle (both sides).
// A: direct per-lane global loads (contiguous 64B spans), depth-2 register prefetch.
// LVL1: h_prev/c_prev are the id-indexed H0h/H0c tables.
template<bool LVL1>
__global__ __launch_bounds__(256, 3) void cell3(
    const _Float16* __restrict__ WTh, const float* __restrict__ tab,
    const int* __restrict__ ids,
    const _Float16* __restrict__ h_prev, const float* __restrict__ c_prev,
    _Float16* __restrict__ h_out, float* __restrict__ c_out,
    int n, int ln, int off)
{
    __shared__ _Float16 Bs[2][80 * 32];        // 5KB per buffer
    const int tid = threadIdx.x, lane = tid & 63, wid = tid >> 6;
    const int l15 = lane & 15, lg = lane >> 4;
    const int rowB = blockIdx.x * 256;
    const int t0 = blockIdx.y * 16;

    // ---- A source pointers (per row-frag): k<256 -> aPA, k>=256 -> aPB
    const _Float16* aPA[4];
    const _Float16* aPB[4];
    #pragma unroll
    for (int rt = 0; rt < 4; ++rt) {
        int row = rowB + wid * 64 + rt * 16 + l15;
        if constexpr (LVL1) {
            int b = row >> 7, j = row & 127;
            int idA = ids[b * NODES_ + 2 * j];
            int idB = ids[b * NODES_ + 2 * j + 1];
            aPA[rt] = h_prev + (size_t)idA * 256 + lg * 8;
            aPB[rt] = h_prev + (size_t)idB * 256 + lg * 8;
        } else {
            aPA[rt] = h_prev + (size_t)row * 512 + lg * 8;
            aPB[rt] = aPA[rt] + 256;
        }
    }
    // ---- B staging source (per-lane, seg pre-swizzled so LDS dest stays linear)
    const int nb0 = tid >> 2;                  // B-tile row 0..63 (round 0)
    const int sg0 = ((tid & 3) ^ (nb0 & 3)) * 8;
    const _Float16* srcB0 = WTh + (size_t)((nb0 >> 4) * 256 + t0 + (nb0 & 15)) * 512 + sg0;
    const _Float16* srcB1 = WTh + (size_t)(1024 + t0 + nb0) * 512 + sg0;   // rows 64..79 (g=4), tid<64

    f32x4 acc[4][5];
    #pragma unroll
    for (int rt = 0; rt < 4; ++rt)
        #pragma unroll
        for (int g = 0; g < 5; ++g) acc[rt][g] = (f32x4)0.f;

    half8 aF[2][4];
    // prologue: stage B(0), load A(0)
    gload16(srcB0, &Bs[0][wid * 512]);
    if (tid < 64) gload16(srcB1, &Bs[0][2048]);
    #pragma unroll
    for (int rt = 0; rt < 4; ++rt) aF[0][rt] = *(const half8*)(aPA[rt]);
    __syncthreads();

    #pragma unroll
    for (int s = 0; s < 16; ++s) {
        const int cur = s & 1, nxt = cur ^ 1;
        if (s < 15) {
            const int k1 = (s + 1) * 32;
            gload16(srcB0 + k1, &Bs[nxt][wid * 512]);
            if (tid < 64) gload16(srcB1 + k1, &Bs[nxt][2048]);
            #pragma unroll
            for (int rt = 0; rt < 4; ++rt)
                aF[nxt][rt] = (k1 < 256) ? *(const half8*)(aPA[rt] + k1)
                                         : *(const half8*)(aPB[rt] + (k1 - 256));
        }
        half8 bF[5];
        #pragma unroll
        for (int g = 0; g < 5; ++g)
            bF[g] = *(const half8*)&Bs[cur][(g * 16 + l15) * 32 + ((lg ^ (l15 & 3)) * 8)];
        #pragma unroll
        for (int rt = 0; rt < 4; ++rt)
            #pragma unroll
            for (int g = 0; g < 5; ++g)
                acc[rt][g] = __builtin_amdgcn_mfma_f32_16x16x32_f16(aF[cur][rt], bF[g], acc[rt][g], 0, 0, 0);
        if (s < 15) __syncthreads();
    }

    // ---- fused epilogue. D: col = lane&15, row = (lane>>4)*4 + q
    const int tcol = t0 + l15;
    #pragma unroll
    for (int rt = 0; rt < 4; ++rt) {
        #pragma unroll
        for (int q = 0; q < 4; ++q) {
            int row = rowB + wid * 64 + rt * 16 + lg * 4 + q;
            int b = row >> ln, j = row & (n - 1);
            int id = ids[b * NODES_ + off + j];
            const float* tp = tab + (size_t)id * 1280 + tcol;
            float c1, c2;
            if constexpr (LVL1) {
                int bb = row >> 7, jj = row & 127;
                int idA = ids[bb * NODES_ + 2 * jj];
                int idB = ids[bb * NODES_ + 2 * jj + 1];
                c1 = c_prev[(size_t)idA * 256 + tcol];
                c2 = c_prev[(size_t)idB * 256 + tcol];
            } else {
                const float* cpp = c_prev + (size_t)row * 512 + tcol;
                c1 = cpp[0]; c2 = cpp[256];
            }
            float vi = sigm(acc[rt][0][q] + tp[0]);
            float vo = sigm(acc[rt][1][q] + tp[256]);
            float vu = tanh_f(acc[rt][2][q] + tp[512]);
            float vf0 = sigm(acc[rt][3][q] + tp[768]);
            float vf1 = sigm(acc[rt][4][q] + tp[1024]);
            float c = vi * vu + vf0 * c1 + vf1 * c2;
            size_t ob = (size_t)row * 256 + tcol;
            h_out[ob] = (_Float16)(vo * tanh_f(c));
            c_out[ob] = c;
        }
    }
}

// pred[b] = relu(h_root[b] @ Wl1 + bl1) @ Wl2 + bl2
__global__ void head_kernel(const _Float16* __restrict__ hroot,
    const float* __restrict__ Wl1, const float* __restrict__ bl1,
    const float* __restrict__ Wl2, const float* __restrict__ bl2,
    float* __restrict__ out)
{
    __shared__ float hrow[H_];
    __shared__ float red[256];
    int b = blockIdx.x; int tid = threadIdx.x;
    hrow[tid] = (float)hroot[(size_t)b * H_ + tid];
    __syncthreads();
    float v = 0.f;
    if (tid < 100) {
        float s = bl1[tid];
        for (int k = 0; k < H_; ++k) s = fmaf(hrow[k], Wl1[k * 100 + tid], s);
        v = fmaxf(s, 0.f) * Wl2[tid];
    }
    red[tid] = v;
    __syncthreads();
    for (int s = 128; s > 0; s >>= 1) { if (tid < s) red[tid] += red[tid + s]; __syncthreads(); }
    if (tid == 0) out[b] = red[0] + bl2[0];
}

extern "C" void kernel_launch(void* const* d_in, const int* in_sizes, int n_in,
                              void* d_out, int out_size, void* d_ws, size_t ws_size,
                              hipStream_t stream) {
    const int*   ids    = (const int*)d_in[0];
    const float* emb    = (const float*)d_in[1];
    const float* Wioux  = (const float*)d_in[2];
    const float* bioux  = (const float*)d_in[3];
    const float* Wiouh1 = (const float*)d_in[4];
    const float* biouh1 = (const float*)d_in[5];
    const float* Wiouh2 = (const float*)d_in[6];
    const float* biouh2 = (const float*)d_in[7];
    const float* Wfx    = (const float*)d_in[8];
    const float* bfx    = (const float*)d_in[9];
    const float* Wfh11  = (const float*)d_in[10];
    const float* bfh11  = (const float*)d_in[11];
    const float* Wfh12  = (const float*)d_in[12];
    const float* bfh12  = (const float*)d_in[13];
    const float* Wfh21  = (const float*)d_in[14];
    const float* bfh21  = (const float*)d_in[15];
    const float* Wfh22  = (const float*)d_in[16];
    const float* bfh22  = (const float*)d_in[17];
    const float* Wl1    = (const float*)d_in[18];
    const float* bl1    = (const float*)d_in[19];
    const float* Wl2    = (const float*)d_in[20];
    const float* bl2    = (const float*)d_in[21];
    float* out = (float*)d_out;

    // ws layout (bytes)
    char* wsb = (char*)d_ws;
    _Float16* WTh = (_Float16*)(wsb);                    //  1,310,720
    float*    tab = (float*)(wsb + 1310720);             // 10,485,760
    _Float16* H0h = (_Float16*)(wsb + 11796480);         //  1,048,576
    float*    H0c = (float*)(wsb + 12845056);            //  2,097,152
    _Float16* hA  = (_Float16*)(wsb + 14942208);         //  8,388,608  (lvl 2,4,6,8 out)
    _Float16* hB  = (_Float16*)(wsb + 23330816);         // 16,777,216  (lvl 1,3,5,7 out)
    float*    cA  = (float*)(wsb + 40108032);            // 16,777,216
    float*    cB  = (float*)(wsb + 56885248);            // 33,554,432  -> ends 90,439,680

    build_WTh<<<dim3(2560), 256, 0, stream>>>(WTh, Wiouh1, Wfh11, Wfh21, Wiouh2, Wfh12, Wfh22);
    build_table<<<dim3(32, 20), 256, 0, stream>>>(tab, emb, Wioux, Wfx,
        bioux, biouh1, biouh2, bfx, bfh11, bfh12, bfh21, bfh22);
    build_h0c0<<<dim3(2048), 256, 0, stream>>>(tab, H0h, H0c);

    // level 1: A gathered from id-indexed H0 tables
    cell3<true><<<dim3(128, 16), 256, 0, stream>>>(WTh, tab, ids, H0h, H0c, hB, cB, 128, 7, 256);

    _Float16 *hp = hB, *hn = hA;
    float    *cp = cB, *cn = cA;
    int off = 384, n = 64, ln = 6;
    for (int lvl = 2; lvl <= 8; ++lvl) {
        int M = B_ * n;
        cell3<false><<<dim3(M / 256, 16), 256, 0, stream>>>(WTh, tab, ids, hp, cp, hn, cn, n, ln, off);
        off += n; n >>= 1; --ln;
        _Float16* t1 = hp; hp = hn; hn = t1;
        float*    t2 = cp; cp = cn; cn = t2;
    }

    head_kernel<<<dim3(256), 256, 0, stream>>>(hp, Wl1, bl1, Wl2, bl2, out);
}